// Round 18
// baseline (202.616 us; speedup 1.0000x reference)
//
#include <hip/hip_runtime.h>
#include <stdint.h>

typedef unsigned int u32;
typedef unsigned long long u64;

// key = ((b*512 + z/2)*512 + y/2)*512 + x/2  in [0, 2^29)
// rec = (key<<3)|off. coarse = rec>>24 (8b), bucket = rec>>17 (15b),
// fine = (rec>>17)&127, half = fine>>6, bin = fine&63,
// local key = (rec>>3) & 0x3FFF (14b).
// part2u internal: pr = (seq<<24) | rec_low24. After repack:
// rec' = (rank<<17) | (lk<<3) | off  (bucket implied by position).
#define LBITS  14
#define LMASK  ((1u << LBITS) - 1u)
#define NBUCK  (1u << (29 - LBITS))      // 32768 fine buckets
#define BWORDS (1u << (LBITS - 5))       // 512 u32 bitmap words / bucket
#define WPL    (BWORDS / 64)             // 8 words per lane (one prefix group)
#define WOPAD  (BWORDS + BWORDS / 32)    // +1 word per 32 -> conflict-free strided access
#define FCAP   224                       // LDS feats/key slots (max bucket cnt ~172)
#define BPB    4                         // pass_emit buckets (waves) per 256-thr block
#define TILE_A 4096                      // part1f tile (16 rec/thread) - 8 blocks/CU
#define RPT    (TILE_A / 256)            // records per thread in part1f (16)
#define CCAP   17408                     // fixed tmp region per coarse bin (2 x HCAP)
#define HCAP   8704                      // half-region (mean 7812, +10sigma)
#define P2T    1024                      // part2u threads (16 waves)
#define RPT2U  ((CCAP + P2T - 1) / P2T)  // 17 read slots per thread in part2u

__device__ __forceinline__ u32 woidx(u32 w) { return w + (w >> 5); }

// wave64 is lockstep on CDNA: intra-wave LDS producer->consumer needs only a
// drained LDS counter, not a block barrier.
__device__ __forceinline__ void wsync() {
    asm volatile("s_waitcnt lgkmcnt(0)" ::: "memory");
}

__device__ __forceinline__ u32 make_key(int4 c) {
    return ((((u32)c.x * 512u + ((u32)c.w >> 1)) * 512u + ((u32)c.z >> 1)) * 512u)
           + ((u32)c.y >> 1);
}

// ---- tiny init: zero the padded coarse-reservation counters
__global__ void zero1(u32* __restrict__ p, u32 g) {
    u32 i = blockIdx.x * 256u + threadIdx.x;
    if (i < g) p[i] = 0u;
}

// ---- part1f: coords -> rec, block hist (atomicAdd return = seq), bulk
// reserve, LDS-stage, coalesced write to fixed coarse regions. (r15-verified)
__global__ void __launch_bounds__(256) part1f(const int4* __restrict__ coords,
        u32* __restrict__ ccur, u32* __restrict__ tmp, int n) {
    __shared__ u32 stage[TILE_A];
    __shared__ u32 hcnt[256];
    __shared__ u32 eb[256];
    __shared__ u32 gb[256];
    __shared__ u32 wtot[4];
    u32 t = threadIdx.x, wave = t >> 6, lane = t & 63u;
    u32 base = blockIdx.x * TILE_A;
    u32 m = min((u32)TILE_A, (u32)n - base);
    hcnt[t] = 0u;
    __syncthreads();
    u32 recv[RPT]; u32 seqv[RPT];
    #pragma unroll
    for (int k = 0; k < RPT; ++k) {
        u32 j = (u32)k * 256u + t;
        if (j < m) {
            int4 c = coords[base + j];
            u32 key = make_key(c);
            u32 off = ((u32)c.y & 1u) | (((u32)c.z & 1u) << 1) | (((u32)c.w & 1u) << 2);
            u32 rec = (key << 3) | off;
            recv[k] = rec;
            seqv[k] = atomicAdd(&hcnt[rec >> 24], 1u);   // hist AND sequence
        }
    }
    __syncthreads();
    // 256-bin exclusive scan: wave-local prefix + cross-wave offset
    u32 v = hcnt[t];
    u32 incl = v;
    #pragma unroll
    for (int d = 1; d < 64; d <<= 1) {
        u32 x = __shfl_up(incl, d);
        if ((int)lane >= d) incl += x;
    }
    if (lane == 63u) wtot[wave] = incl;
    __syncthreads();
    u32 off = (wave > 0u ? wtot[0] : 0u) + (wave > 1u ? wtot[1] : 0u)
            + (wave > 2u ? wtot[2] : 0u);
    u32 excl = off + incl - v;
    // bulk reserve: one atomic per (block,bin); counters padded to own 64B line
    u32 gbase = atomicAdd(&ccur[t * 16u], v);
    eb[t] = excl;
    gb[t] = t * (u32)CCAP + gbase - excl;  // dst = c*CCAP + gbase + (stage_idx - excl)
    __syncthreads();
    #pragma unroll
    for (int k = 0; k < RPT; ++k) {
        u32 j = (u32)k * 256u + t;
        if (j < m) {
            u32 rec = recv[k];
            stage[eb[rec >> 24] + seqv[k]] = rec;        // atomic-free place
        }
    }
    __syncthreads();
    for (u32 j = t; j < m; j += 256u) {
        u32 rec = stage[j];
        tmp[gb[rec >> 24] + j] = rec;      // runs of ~16 -> coalesced
    }
}

// ---- part2u: one block per (coarse, half) = 512 blocks, 2 blocks/CU.
// Reads whole coarse region, keeps its half (fine bit 6), groups into LDS,
// dedup + rank (wof8 + walk) + repack, writes to fixed half-region; emits
// cstart/bcnt/ucnt/lexc(in-half)/htot.
__global__ void __launch_bounds__(P2T) part2u(u32* __restrict__ tmp,
        const u32* __restrict__ ccur, u32* __restrict__ cstart,
        u32* __restrict__ bcnt, u32* __restrict__ ucnt,
        u32* __restrict__ lexc, u32* __restrict__ htot) {
    __shared__ u32 stage[HCAP];           // 34.8 KB
    __shared__ u32 sh_h[64];
    __shared__ u32 lstart[64];
    __shared__ u32 cnts[64];
    __shared__ u32 ucl[64];
    __shared__ u32 shLh[1];
    __shared__ u32 bm[16][WOPAD];         // 33.9 KB per-wave bitmaps
    __shared__ u32 wof8[16][64];          // 4 KB per-wave lane-group prefixes
    u32 t = threadIdx.x, wave = t >> 6, lane = t & 63u;
    u32 c = blockIdx.x >> 1, h = blockIdx.x & 1u;
    u32 base = c * (u32)CCAP;
    u32 hbase = base + h * (u32)HCAP;
    u32 L = ccur[c * 16u];
    if (t < 64u) sh_h[t] = 0u;
    __syncthreads();
    u32 recv[RPT2U];
    #pragma unroll
    for (int k = 0; k < RPT2U; ++k) {
        u32 j = (u32)k * P2T + t;
        recv[k] = 0xFFFFFFFFu;
        if (j < L) {
            u32 rec = tmp[base + j];
            if (((rec >> 23) & 1u) == h) {             // keep own half
                u32 sq = atomicAdd(&sh_h[(rec >> 17) & 63u], 1u);  // hist AND seq
                recv[k] = (sq << 24) | (rec & 0xFFFFFFu);
            }
        }
    }
    __syncthreads();
    // 64-bin exclusive scan (wave 0) + table emit
    if (t < 64u) {
        u32 v = sh_h[t];
        u32 incl = v;
        #pragma unroll
        for (int d = 1; d < 64; d <<= 1) {
            u32 x = __shfl_up(incl, d);
            if ((int)lane >= d) incl += x;
        }
        u32 excl = incl - v;
        lstart[t] = excl;
        cnts[t] = v;
        u32 bucket = (c << 7) | (h << 6) | t;
        cstart[bucket] = hbase + excl;     // exact-packed start in half-region
        bcnt[bucket] = v;
        if (t == 63u) shLh[0] = incl;      // half total
    }
    __syncthreads();
    u32 Lh = shLh[0];
    // atomic-free place into bucket-grouped LDS order (keep low 17: lk+off)
    #pragma unroll
    for (int k = 0; k < RPT2U; ++k) {
        u32 pr = recv[k];
        if (pr != 0xFFFFFFFFu)
            stage[lstart[(pr >> 17) & 63u] + (pr >> 24)] = pr & 0x1FFFFu;
    }
    __syncthreads();
    // dedup + rank + repack: wave w handles buckets [w*4, w*4+4)
    u32* B = bm[wave];
    u32* W8 = wof8[wave];
    for (u32 bi = 0; bi < 4u; ++bi) {
        u32 b = wave * 4u + bi;
        #pragma unroll
        for (int j = 0; j < WPL; ++j) B[woidx(lane * WPL + j)] = 0u;
        wsync();
        u32 s0 = lstart[b], cnt = cnts[b];
        for (u32 i = s0 + lane; i < s0 + cnt; i += 64u) {
            u32 lk = (stage[i] >> 3) & LMASK;
            atomicOr(&B[woidx(lk >> 5)], 1u << (lk & 31u));
        }
        wsync();
        u32 sum = 0;
        #pragma unroll
        for (int j = 0; j < WPL; ++j) sum += __popc(B[woidx(lane * WPL + j)]);
        u32 inc2 = sum;
        #pragma unroll
        for (int d = 1; d < 64; d <<= 1) {
            u32 x = __shfl_up(inc2, d);
            if ((int)lane >= d) inc2 += x;
        }
        W8[lane] = inc2 - sum;             // lane-group exclusive prefix
        if (lane == 63u) ucl[b] = inc2;
        wsync();
        for (u32 i = s0 + lane; i < s0 + cnt; i += 64u) {
            u32 rec = stage[i];
            u32 lk = (rec >> 3) & LMASK;
            u32 w = lk >> 5, bit = lk & 31u;
            u32 g = w >> 3;
            u32 r = W8[g];
            for (u32 k = g * 8u; k < w; ++k) r += __popc(B[woidx(k)]);
            r += __popc(B[woidx(w)] & ((1u << bit) - 1u));
            stage[i] = (r << 17) | (rec & 0x1FFFFu);   // rank-carrying record
        }
        wsync();
    }
    __syncthreads();
    // write repacked grouped records to own half-region (coalesced)
    for (u32 j = t; j < Lh; j += P2T) tmp[hbase + j] = stage[j];
    if (t < 64u) ucnt[(c << 7) | (h << 6) | t] = ucl[t];
    __syncthreads();
    // local 64-bucket unique scan -> lexc (in-half prefix) + htot[(c<<1)|h]
    if (t < 64u) {
        u32 uv = ucl[t];
        u32 incl2 = uv;
        #pragma unroll
        for (int d = 1; d < 64; d <<= 1) {
            u32 x = __shfl_up(incl2, d);
            if ((int)lane >= d) incl2 += x;
        }
        lexc[(c << 7) | (h << 6) | t] = incl2 - uv;
        if (t == 63u) htot[(c << 1) | h] = incl2;
    }
}

// ---- one wave per fine bucket, no block barriers, no bitmap: records carry
// ranks. F[rank] += ksc[off]; K[rank] = lk (benign same-value race). Emit is
// uniform lane-strided coalesced. Each wave also pads its slice of [U, n).
__global__ void __launch_bounds__(256) pass_emit(const u32* __restrict__ buckrec,
        const u32* __restrict__ cstart, const u32* __restrict__ bcnt,
        const u32* __restrict__ ucnt, const u32* __restrict__ lexc,
        const u32* __restrict__ htot, const float* __restrict__ kern,
        float4* __restrict__ rows, float* __restrict__ feats, int n) {
    __shared__ float fl[BPB][FCAP];
    __shared__ u32 kl[BPB][FCAP];
    __shared__ float ksc[BPB][8];
    u32 wave = threadIdx.x >> 6, lane = threadIdx.x & 63u;
    u32 bucket = blockIdx.x * BPB + wave;
    float* F = fl[wave];
    u32* K = kl[wave];
    #pragma unroll
    for (u32 j = lane; j < FCAP; j += 64u) F[j] = 0.f;
    if (lane < 8u) ksc[wave][lane] = (float)(1u << lane) * kern[lane];
    wsync();
    u32 start = cstart[bucket];
    u32 cnt = bcnt[bucket];
    u32 uc = ucnt[bucket];
    // half-unique base + grand total, redundantly per wave (htot is 2KB, L2-hit)
    u32 ch = bucket >> 6;                  // half index [0,512)
    u32 cb = 0, Uall = 0;
    #pragma unroll
    for (int k = 0; k < 8; ++k) {
        u32 j = (u32)k * 64u + lane;
        u32 uv = htot[j];
        Uall += uv;
        cb += (j < ch) ? uv : 0u;
    }
    #pragma unroll
    for (int d = 1; d < 64; d <<= 1) {
        cb += __shfl_xor(cb, d);
        Uall += __shfl_xor(Uall, d);
    }
    u32 base = cb + lexc[bucket];
    for (u32 i = start + lane; i < start + cnt; i += 64u) {
        u32 rec = buckrec[i];
        u32 r = rec >> 17;
        atomicAdd(&F[r], ksc[wave][rec & 7u]);
        K[r] = (rec >> 3) & LMASK;          // same value from all writers
    }
    wsync();
    u32 keyhi = bucket << LBITS;
    for (u32 j = lane; j < uc; j += 64u) {
        u32 key = keyhi | K[j];
        rows[base + j] = make_float4((float)(key >> 27), (float)(key & 511u),
                                     (float)((key >> 9) & 511u),
                                     (float)((key >> 18) & 511u));
        feats[base + j] = F[j];
    }
    // pad slice of [U, n)
    u32 len = (u32)n - Uall;
    u32 per = (len + (u32)NBUCK - 1u) / (u32)NBUCK;
    u32 ps = Uall + bucket * per;
    u32 pe = min(ps + per, (u32)n);
    for (u32 i = ps + lane; i < pe; i += 64u) {
        rows[i] = make_float4(-1.f, -1.f, -1.f, -1.f);
        feats[i] = 0.f;
    }
}

extern "C" void kernel_launch(void* const* d_in, const int* in_sizes, int n_in,
                              void* d_out, int out_size, void* d_ws, size_t ws_size,
                              hipStream_t stream) {
    const int n = in_sizes[0] / 4;               // 4,000,000 points
    const int4* coords = (const int4*)d_in[0];
    const float* kern  = (const float*)d_in[1];
    const u32 NT = ((u32)n + TILE_A - 1) / TILE_A;        // 977 tiles

    u32* wsp = (u32*)d_ws;
    u32* tmp     = wsp;                    // 256*CCAP coarse regions (17.8 MB)
    u32* ccur    = tmp + 256 * CCAP;       // 256*16 padded coarse counters (1/64B line)
    u32* cstart  = ccur + 256 * 16;        // NBUCK exact-packed bucket starts
    u32* bcnt    = cstart + NBUCK;         // NBUCK bucket record counts
    u32* ucnt    = bcnt + NBUCK;           // NBUCK bucket unique counts
    u32* lexc    = ucnt + NBUCK;           // NBUCK in-half unique prefixes
    u32* htot    = lexc + NBUCK;           // 512 half unique totals

    float4* rows  = (float4*)d_out;                              // n rows
    float*  feats = (float*)((char*)d_out + (size_t)n * 16);     // n fp32

    zero1<<<16, 256, 0, stream>>>(ccur, 256 * 16);
    part1f<<<NT, 256, 0, stream>>>(coords, ccur, tmp, n);
    part2u<<<512, P2T, 0, stream>>>(tmp, ccur, cstart, bcnt, ucnt, lexc, htot);
    pass_emit<<<NBUCK / BPB, 256, 0, stream>>>(tmp, cstart, bcnt, ucnt, lexc, htot,
                                               kern, rows, feats, n);
}

// Round 19
// 191.463 us; speedup vs baseline: 1.0583x; 1.0583x over previous
//
#include <hip/hip_runtime.h>
#include <stdint.h>

typedef unsigned int u32;
typedef unsigned long long u64;

// key = ((b*512 + z/2)*512 + y/2)*512 + x/2  in [0, 2^29)
// rec = (key<<3)|off. coarse = rec>>24 (8b), bucket = rec>>17 (15b),
// local key = (rec>>3) & 0x3FFF (14b).
// part2u internal: pr = (seq<<24) | rec_low24 (fine 7 + lk 14 + off 3).
// After part2u repack: rec' = (rank<<17) | (lk<<3) | off  (bucket implied).
#define LBITS  14
#define LMASK  ((1u << LBITS) - 1u)
#define NBUCK  (1u << (29 - LBITS))      // 32768 fine buckets
#define BWORDS (1u << (LBITS - 5))       // 512 u32 bitmap words / bucket
#define WPL    (BWORDS / 64)             // 8 words per lane (one prefix group)
#define WOPAD  (BWORDS + BWORDS / 32)    // +1 word per 32 -> conflict-free strided access
#define FCAP   224                       // LDS feats/key slots (max bucket cnt ~172)
#define BPB    4                         // pass_emit buckets (waves) per 256-thr block
#define TILE_A 4096                      // part1f tile (16 rec/thread) - 8 blocks/CU
#define RPT    (TILE_A / 256)            // records per thread in part1f (16)
#define CCAP   16384                     // fixed tmp region per coarse bin (mean 15625, +6sigma)
#define P2T    1024                      // part2u threads (16 waves)
#define RPT2U  (CCAP / P2T)              // 16 records per thread in part2u

__device__ __forceinline__ u32 woidx(u32 w) { return w + (w >> 5); }

// wave64 is lockstep on CDNA: intra-wave LDS producer->consumer needs only a
// drained LDS counter, not a block barrier.
__device__ __forceinline__ void wsync() {
    asm volatile("s_waitcnt lgkmcnt(0)" ::: "memory");
}

__device__ __forceinline__ u32 make_key(int4 c) {
    return ((((u32)c.x * 512u + ((u32)c.w >> 1)) * 512u + ((u32)c.z >> 1)) * 512u)
           + ((u32)c.y >> 1);
}

// ---- tiny init: zero the padded coarse-reservation counters
__global__ void zero1(u32* __restrict__ p, u32 g) {
    u32 i = blockIdx.x * 256u + threadIdx.x;
    if (i < g) p[i] = 0u;
}

// ---- part1f: coords -> rec, single block hist (atomicAdd return = seq),
// bulk reserve, atomic-free place, coalesced write to fixed coarse regions.
__global__ void __launch_bounds__(256) part1f(const int4* __restrict__ coords,
        u32* __restrict__ ccur, u32* __restrict__ tmp, int n) {
    __shared__ u32 stage[TILE_A];
    __shared__ u32 hcnt[256];
    __shared__ u32 eb[256];
    __shared__ u32 gb[256];
    __shared__ u32 wtot[4];
    u32 t = threadIdx.x, wave = t >> 6, lane = t & 63u;
    u32 base = blockIdx.x * TILE_A;
    u32 m = min((u32)TILE_A, (u32)n - base);
    hcnt[t] = 0u;
    __syncthreads();
    u32 recv[RPT]; u32 seqv[RPT];
    #pragma unroll
    for (int k = 0; k < RPT; ++k) {
        u32 j = (u32)k * 256u + t;
        if (j < m) {
            int4 c = coords[base + j];
            u32 key = make_key(c);
            u32 off = ((u32)c.y & 1u) | (((u32)c.z & 1u) << 1) | (((u32)c.w & 1u) << 2);
            u32 rec = (key << 3) | off;
            recv[k] = rec;
            seqv[k] = atomicAdd(&hcnt[rec >> 24], 1u);   // hist AND sequence
        }
    }
    __syncthreads();
    // 256-bin exclusive scan: wave-local prefix + cross-wave offset
    u32 v = hcnt[t];
    u32 incl = v;
    #pragma unroll
    for (int d = 1; d < 64; d <<= 1) {
        u32 x = __shfl_up(incl, d);
        if ((int)lane >= d) incl += x;
    }
    if (lane == 63u) wtot[wave] = incl;
    __syncthreads();
    u32 off = (wave > 0u ? wtot[0] : 0u) + (wave > 1u ? wtot[1] : 0u)
            + (wave > 2u ? wtot[2] : 0u);
    u32 excl = off + incl - v;
    // bulk reserve: one atomic per (block,bin); counters padded to own 64B line
    u32 gbase = atomicAdd(&ccur[t * 16u], v);
    eb[t] = excl;
    gb[t] = (t << 14) + gbase - excl;      // dst = c*CCAP + gbase + (stage_idx - excl)
    __syncthreads();
    #pragma unroll
    for (int k = 0; k < RPT; ++k) {
        u32 j = (u32)k * 256u + t;
        if (j < m) {
            u32 rec = recv[k];
            stage[eb[rec >> 24] + seqv[k]] = rec;        // atomic-free place
        }
    }
    __syncthreads();
    for (u32 j = t; j < m; j += 256u) {
        u32 rec = stage[j];
        tmp[gb[rec >> 24] + j] = rec;      // runs of ~16 -> coalesced
    }
}

// ---- part2u: one block per coarse bin. Single hist (return = seq, packed into
// record high bits), atomic-free bucket grouping in LDS, dedup + rank + repack
// as (rank<<17)|low17, write back in place; emit cstart/bcnt/ucnt/lexc/utot.
__global__ void __launch_bounds__(P2T) part2u(u32* __restrict__ tmp,
        const u32* __restrict__ ccur, u32* __restrict__ cstart,
        u32* __restrict__ bcnt, u32* __restrict__ ucnt,
        u32* __restrict__ lexc, u32* __restrict__ utot) {
    __shared__ u32 stage[CCAP];           // 64 KB
    __shared__ u32 h[128];
    __shared__ u32 lstart[128];
    __shared__ u32 cnts[128];
    __shared__ u32 ucl[128];
    __shared__ u32 wtot[2];
    __shared__ u32 bm[16][WOPAD];         // 33.8 KB per-wave bitmaps
    __shared__ u32 Wt[16][BWORDS];        // 32 KB per-wave word-prefix tables
    u32 t = threadIdx.x, wave = t >> 6, lane = t & 63u;
    u32 c = blockIdx.x;
    u32 base = c << 14;                    // c * CCAP
    u32 L = ccur[c * 16u];
    if (t < 128u) h[t] = 0u;
    __syncthreads();
    u32 recv[RPT2U];
    #pragma unroll
    for (int k = 0; k < RPT2U; ++k) {
        u32 j = (u32)k * P2T + t;
        if (j < L) {
            u32 rec = tmp[base + j];
            u32 sq = atomicAdd(&h[(rec >> 17) & 127u], 1u);   // hist AND sequence
            recv[k] = (sq << 24) | (rec & 0xFFFFFFu);
        }
    }
    __syncthreads();
    // 128-bin exclusive scan (2 waves) + table emit
    u32 v = 0, incl = 0;
    if (t < 128u) {
        v = h[t];
        incl = v;
        #pragma unroll
        for (int d = 1; d < 64; d <<= 1) {
            u32 x = __shfl_up(incl, d);
            if ((int)lane >= d) incl += x;
        }
        if (lane == 63u) wtot[t >> 6] = incl;
    }
    __syncthreads();
    if (t < 128u) {
        u32 off = (t >= 64u) ? wtot[0] : 0u;
        u32 excl = off + incl - v;
        lstart[t] = excl;
        cnts[t] = v;
        u32 bucket = (c << 7) | t;
        cstart[bucket] = base + excl;      // exact-packed start
        bcnt[bucket] = v;
    }
    __syncthreads();
    // atomic-free place into bucket-grouped LDS order (keep low 17: lk+off)
    #pragma unroll
    for (int k = 0; k < RPT2U; ++k) {
        u32 j = (u32)k * P2T + t;
        if (j < L) {
            u32 pr = recv[k];
            stage[lstart[(pr >> 17) & 127u] + (pr >> 24)] = pr & 0x1FFFFu;
        }
    }
    __syncthreads();
    // dedup + rank + repack: wave w handles buckets [w*8, w*8+8)
    u32* B = bm[wave];
    u32* W = Wt[wave];
    for (u32 bi = 0; bi < 8u; ++bi) {
        u32 b = wave * 8u + bi;
        #pragma unroll
        for (int j = 0; j < WPL; ++j) B[woidx(lane * WPL + j)] = 0u;
        wsync();
        u32 s0 = lstart[b], cnt = cnts[b];
        for (u32 i = s0 + lane; i < s0 + cnt; i += 64u) {
            u32 lk = (stage[i] >> 3) & LMASK;
            atomicOr(&B[woidx(lk >> 5)], 1u << (lk & 31u));
        }
        wsync();
        u32 pc[WPL]; u32 sum = 0;
        #pragma unroll
        for (int j = 0; j < WPL; ++j) { pc[j] = __popc(B[woidx(lane * WPL + j)]); sum += pc[j]; }
        u32 inc2 = sum;
        #pragma unroll
        for (int d = 1; d < 64; d <<= 1) {
            u32 x = __shfl_up(inc2, d);
            if ((int)lane >= d) inc2 += x;
        }
        u32 lex = inc2 - sum;
        {
            u32 r = lex;
            #pragma unroll
            for (int j = 0; j < WPL; ++j) { W[((u32)j << 6) | lane] = r; r += pc[j]; }
        }
        if (lane == 63u) ucl[b] = inc2;
        wsync();
        for (u32 i = s0 + lane; i < s0 + cnt; i += 64u) {
            u32 rec = stage[i];
            u32 lk = (rec >> 3) & LMASK;
            u32 w = lk >> 5, bit = lk & 31u;
            u32 r = W[((w & 7u) << 6) | (w >> 3)]
                  + __popc(B[woidx(w)] & ((1u << bit) - 1u));
            stage[i] = (r << 17) | (rec & 0x1FFFFu);   // rank-carrying record
        }
        wsync();
    }
    __syncthreads();
    // write repacked grouped records back in place (coalesced)
    for (u32 j = t; j < L; j += P2T) tmp[base + j] = stage[j];
    if (t < 128u) ucnt[(c << 7) | t] = ucl[t];
    __syncthreads();
    // local 128-bucket unique scan -> lexc (in-coarse prefix) + utot[c]
    u32 uv = 0, incl2 = 0;
    if (t < 128u) {
        uv = ucl[t];
        incl2 = uv;
        #pragma unroll
        for (int d = 1; d < 64; d <<= 1) {
            u32 x = __shfl_up(incl2, d);
            if ((int)lane >= d) incl2 += x;
        }
        if (lane == 63u) wtot[t >> 6] = incl2;
    }
    __syncthreads();
    if (t < 128u) {
        u32 off = (t >= 64u) ? wtot[0] : 0u;
        lexc[(c << 7) | t] = off + incl2 - uv;
        if (t == 127u) utot[c] = wtot[0] + incl2;
    }
}

// ---- one wave per fine bucket, no block barriers, no bitmap: records carry
// ranks. F[rank] += ksc[off]; klds[rank] = lk (benign same-value race). Emit is
// uniform lane-strided coalesced. Each wave also pads its slice of [U, n).
__global__ void __launch_bounds__(256) pass_emit(const u32* __restrict__ buckrec,
        const u32* __restrict__ cstart, const u32* __restrict__ bcnt,
        const u32* __restrict__ ucnt, const u32* __restrict__ lexc,
        const u32* __restrict__ utot, const float* __restrict__ kern,
        float4* __restrict__ rows, float* __restrict__ feats, int n) {
    __shared__ float fl[BPB][FCAP];
    __shared__ u32 kl[BPB][FCAP];
    __shared__ float ksc[BPB][8];
    u32 wave = threadIdx.x >> 6, lane = threadIdx.x & 63u;
    u32 bucket = blockIdx.x * BPB + wave;
    float* F = fl[wave];
    u32* K = kl[wave];
    #pragma unroll
    for (u32 j = lane; j < FCAP; j += 64u) F[j] = 0.f;
    if (lane < 8u) ksc[wave][lane] = (float)(1u << lane) * kern[lane];
    wsync();
    u32 start = cstart[bucket];
    u32 cnt = bcnt[bucket];
    u32 uc = ucnt[bucket];
    // coarse unique base + grand total, redundantly per wave (utot is 1KB, L2-hit)
    u32 c = bucket >> 7;
    u32 cb = 0, Uall = 0;
    #pragma unroll
    for (int k = 0; k < 4; ++k) {
        u32 j = (u32)k * 64u + lane;
        u32 uv = utot[j];
        Uall += uv;
        cb += (j < c) ? uv : 0u;
    }
    #pragma unroll
    for (int d = 1; d < 64; d <<= 1) {
        cb += __shfl_xor(cb, d);
        Uall += __shfl_xor(Uall, d);
    }
    u32 base = cb + lexc[bucket];
    for (u32 i = start + lane; i < start + cnt; i += 64u) {
        u32 rec = buckrec[i];
        u32 r = rec >> 17;
        atomicAdd(&F[r], ksc[wave][rec & 7u]);
        K[r] = (rec >> 3) & LMASK;          // same value from all writers
    }
    wsync();
    u32 keyhi = bucket << LBITS;
    for (u32 j = lane; j < uc; j += 64u) {
        u32 key = keyhi | K[j];
        rows[base + j] = make_float4((float)(key >> 27), (float)(key & 511u),
                                     (float)((key >> 9) & 511u),
                                     (float)((key >> 18) & 511u));
        feats[base + j] = F[j];
    }
    // pad slice of [U, n): wave vid == bucket handles per elements
    u32 len = (u32)n - Uall;
    u32 per = (len + (u32)NBUCK - 1u) / (u32)NBUCK;
    u32 ps = Uall + bucket * per;
    u32 pe = min(ps + per, (u32)n);
    for (u32 i = ps + lane; i < pe; i += 64u) {
        rows[i] = make_float4(-1.f, -1.f, -1.f, -1.f);
        feats[i] = 0.f;
    }
}

extern "C" void kernel_launch(void* const* d_in, const int* in_sizes, int n_in,
                              void* d_out, int out_size, void* d_ws, size_t ws_size,
                              hipStream_t stream) {
    const int n = in_sizes[0] / 4;               // 4,000,000 points
    const int4* coords = (const int4*)d_in[0];
    const float* kern  = (const float*)d_in[1];
    const u32 NT = ((u32)n + TILE_A - 1) / TILE_A;        // 977 tiles

    u32* wsp = (u32*)d_ws;
    u32* tmp     = wsp;                    // 256*CCAP coarse regions; regrouped in place
    u32* ccur    = tmp + 256 * CCAP;       // 256*16 padded coarse counters (1/64B line)
    u32* cstart  = ccur + 256 * 16;        // NBUCK exact-packed bucket starts
    u32* bcnt    = cstart + NBUCK;         // NBUCK bucket record counts
    u32* ucnt    = bcnt + NBUCK;           // NBUCK bucket unique counts
    u32* lexc    = ucnt + NBUCK;           // NBUCK in-coarse unique prefixes
    u32* utot    = lexc + NBUCK;           // 256 coarse unique totals

    float4* rows  = (float4*)d_out;                              // n rows
    float*  feats = (float*)((char*)d_out + (size_t)n * 16);     // n fp32

    zero1<<<16, 256, 0, stream>>>(ccur, 256 * 16);
    part1f<<<NT, 256, 0, stream>>>(coords, ccur, tmp, n);
    part2u<<<256, P2T, 0, stream>>>(tmp, ccur, cstart, bcnt, ucnt, lexc, utot);
    pass_emit<<<NBUCK / BPB, 256, 0, stream>>>(tmp, cstart, bcnt, ucnt, lexc, utot,
                                               kern, rows, feats, n);
}